// Round 1
// baseline (599.880 us; speedup 1.0000x reference)
//
#include <hip/hip_runtime.h>
#include <math.h>

typedef __attribute__((ext_vector_type(8))) short short8;
typedef __attribute__((ext_vector_type(4))) float f32x4;
typedef __attribute__((ext_vector_type(4))) float f4;
typedef __attribute__((ext_vector_type(4))) unsigned short us4;

#define MFMA16(a,b,c) __builtin_amdgcn_mfma_f32_16x16x32_bf16(a,b,c,0,0,0)

__device__ __forceinline__ unsigned short f2bf(float f) {
  unsigned int u = __float_as_uint(f);
  u = (u + 0x7FFFu + ((u >> 16) & 1u)) >> 16;   // RNE
  return (unsigned short)u;
}
__device__ __forceinline__ float bf2f(unsigned short b) {
  return __uint_as_float(((unsigned int)b) << 16);
}

typedef const __attribute__((address_space(1))) unsigned int* gas_t;
typedef __attribute__((address_space(3))) unsigned int* las_t;
__device__ __forceinline__ void gl16(const void* g, void* l) {
  __builtin_amdgcn_global_load_lds((gas_t)g, (las_t)l, 16, 0, 0);
}

// ---------------- f32 -> bf16 convert ----------------
__global__ void cvt_f32_bf16(const float* __restrict__ in,
                             unsigned short* __restrict__ out, int n4) {
  int i = blockIdx.x * blockDim.x + threadIdx.x;
  const int stride = gridDim.x * blockDim.x;
  for (; i < n4; i += stride) {
    f4 v = ((const f4*)in)[i];
    us4 o;
    o[0] = f2bf(v[0]); o[1] = f2bf(v[1]); o[2] = f2bf(v[2]); o[3] = f2bf(v[3]);
    ((us4*)out)[i] = o;
  }
}

// ---------------- NT GEMM: out[m][n] = sum_k A[m][k]*B[n][k] + bias[n] ----------------
// 128x128 tile, BK=32, 4 waves each 64x64, m97-style global_load_lds staging.
template<int F32OUT>
__global__ __launch_bounds__(256)
void gemm_bt(const unsigned short* __restrict__ A,
             const unsigned short* __restrict__ B,
             const float* __restrict__ bias,
             unsigned short* __restrict__ obf,
             float* __restrict__ of32,
             int K, int ldo)
{
  const int tid = threadIdx.x;
  const int wave = tid >> 6, lane = tid & 63, lg = lane >> 4, lr = lane & 15;
  const int wr = wave >> 1, wc = wave & 1;
  const int m0 = blockIdx.y * 128, n0 = blockIdx.x * 128;

  __shared__ __align__(16) unsigned short Al[128 * 32];
  __shared__ __align__(16) unsigned short Bl[128 * 32];

  f32x4 acc[4][4];
#pragma unroll
  for (int m = 0; m < 4; ++m)
#pragma unroll
    for (int n = 0; n < 4; ++n) acc[m][n] = (f32x4){0.f, 0.f, 0.f, 0.f};

  const int r0 = tid >> 2, r1 = (tid + 256) >> 2;
  const int c0 = (tid & 3) * 8;
  const long arow0 = (long)(m0 + r0) * K, arow1 = (long)(m0 + r1) * K;
  const long brow0 = (long)(n0 + r0) * K, brow1 = (long)(n0 + r1) * K;

  for (int k0 = 0; k0 < K; k0 += 32) {
    gl16(A + arow0 + k0 + c0, (char*)Al + tid * 16);
    gl16(A + arow1 + k0 + c0, (char*)Al + (tid + 256) * 16);
    gl16(B + brow0 + k0 + c0, (char*)Bl + tid * 16);
    gl16(B + brow1 + k0 + c0, (char*)Bl + (tid + 256) * 16);
    __syncthreads();
    short8 af[4], bf[4];
#pragma unroll
    for (int m = 0; m < 4; ++m)
      af[m] = *(const short8*)(Al + (wr * 64 + m * 16 + lr) * 32 + lg * 8);
#pragma unroll
    for (int n = 0; n < 4; ++n)
      bf[n] = *(const short8*)(Bl + (wc * 64 + n * 16 + lr) * 32 + lg * 8);
#pragma unroll
    for (int m = 0; m < 4; ++m)
#pragma unroll
      for (int n = 0; n < 4; ++n)
        acc[m][n] = MFMA16(af[m], bf[n], acc[m][n]);
    __syncthreads();
  }

#pragma unroll
  for (int n = 0; n < 4; ++n) {
    const int col = n0 + wc * 64 + n * 16 + lr;
    const float bs = bias[col];
#pragma unroll
    for (int m = 0; m < 4; ++m) {
      const int row = m0 + wr * 64 + m * 16 + lg * 4;
#pragma unroll
      for (int r = 0; r < 4; ++r) {
        float v = acc[m][n][r] + bs;
        if (F32OUT) of32[(long)(row + r) * ldo + col] = v;
        else        obf[(long)(row + r) * ldo + col] = f2bf(v);
      }
    }
  }
}

// ---------------- fused RMSNorm + RoPE (in-place on bf16 qkv cols) ----------------
// One block per row; colOff selects Q (0) or K (1536); oscale folds softmax scale*log2e into Q.
__global__ __launch_bounds__(256)
void normrope(unsigned short* __restrict__ qkv, const float* __restrict__ g,
              const float* __restrict__ fc, const float* __restrict__ fs,
              int colOff, float oscale)
{
  const int l = blockIdx.x, tid = threadIdx.x;
  __shared__ float rowbuf[1536];
  __shared__ float sred[4];
  unsigned short* rp = qkv + (long)l * 4608 + colOff;

  float ss = 0.f;
  if (tid < 192) {
    short8 v = *(const short8*)(rp + tid * 8);
#pragma unroll
    for (int e = 0; e < 8; ++e) {
      float f = bf2f((unsigned short)v[e]);
      rowbuf[tid * 8 + e] = f;
      ss += f * f;
    }
  }
#pragma unroll
  for (int m = 32; m; m >>= 1) ss += __shfl_xor(ss, m, 64);
  if ((tid & 63) == 0) sred[tid >> 6] = ss;
  __syncthreads();
  const float rs = rsqrtf((sred[0] + sred[1] + sred[2] + sred[3]) * (1.f / 1536.f) + 1e-6f);

  const int f_ = l / 880, rem = l % 880, h_ = rem / 40, w_ = rem % 40;
#pragma unroll
  for (int j = 0; j < 3; ++j) {
    int p = tid + j * 256;           // pair index 0..767
    int head = p >> 6, c = p & 63;
    int e = head * 128 + 2 * c;
    int tr = (c < 22) ? f_ : ((c < 43) ? h_ : w_);
    float co = fc[tr * 64 + c], si = fs[tr * 64 + c];
    float xr = rowbuf[e] * rs * g[e];
    float xi = rowbuf[e + 1] * rs * g[e + 1];
    float yr = (xr * co - xi * si) * oscale;
    float yi = (xr * si + xi * co) * oscale;
    unsigned int pk = (unsigned int)f2bf(yr) | ((unsigned int)f2bf(yi) << 16);
    *(unsigned int*)(rp + e) = pk;
  }
}

// ---------------- chunked sink+window attention ----------------
// grid (28 qtiles, 4 chunks, 12 heads); 4 waves x 16 q-rows; KV tile 64.
__global__ __launch_bounds__(256)
void attn_kern(const unsigned short* __restrict__ qkv,
               unsigned short* __restrict__ ob)
{
  const int qt = blockIdx.x, ci = blockIdx.y, h = blockIdx.z;
  const int tid = threadIdx.x, wave = tid >> 6, lane = tid & 63;
  const int lg = lane >> 4, lr = lane & 15;
  const int chunk_start = ci * 1760, chunk_end = chunk_start + 1760;
  const int wstart = (ci == 0) ? 880 : ci * 1760;
  const int kvlen = 880 + (chunk_end - wstart);     // 1760 or 2640
  const int q0 = chunk_start + qt * 64;

  __shared__ __align__(16) unsigned short Kl[64 * 128];   // [kv][d], swizzled ^((kv&7)<<4)
  __shared__ __align__(16) unsigned short Vt[128 * 64];   // [d][kv], swizzled ^(((d&7)^((d>>3)&7))<<4)
  __shared__ __align__(16) unsigned short Pl[4][16 * 64]; // per-wave P, swizzled ^((row&7)<<4)

  int qr = q0 + wave * 16 + lr;
  if (qr >= chunk_end) qr = chunk_end - 1;
  const unsigned short* qp = qkv + (long)qr * 4608 + h * 128;
  short8 qf[4];
#pragma unroll
  for (int kk = 0; kk < 4; ++kk) qf[kk] = *(const short8*)(qp + kk * 32 + lg * 8);

  f32x4 Oc[8];
#pragma unroll
  for (int i = 0; i < 8; ++i) Oc[i] = (f32x4){0.f, 0.f, 0.f, 0.f};
  float mrow[4] = {-1e30f, -1e30f, -1e30f, -1e30f};
  float lrow[4] = {0.f, 0.f, 0.f, 0.f};

  const int nt = (kvlen + 63) >> 6;
  for (int t = 0; t < nt; ++t) {
    // --- stage K via global_load_lds, inverse-swizzled source chunk ---
#pragma unroll
    for (int i = 0; i < 4; ++i) {
      int s = i * 256 + tid;
      int kvl = s >> 4;
      int dc = (s & 15) ^ (kvl & 7);
      int j = t * 64 + kvl; j = j < kvlen ? j : kvlen - 1;
      int gk = j < 880 ? j : wstart + (j - 880);
      gl16(qkv + (long)gk * 4608 + 1536 + h * 128 + dc * 8, (char*)Kl + s * 16);
    }
    // --- stage V transposed (reg path, packed b32 writes) ---
#pragma unroll
    for (int i = 0; i < 2; ++i) {
      int task = i * 256 + tid;
      int dc = task & 15, kp = task >> 4;
      int kvl = kp * 2;
      int j0 = t * 64 + kvl, j1 = j0 + 1;
      j0 = j0 < kvlen ? j0 : kvlen - 1;
      j1 = j1 < kvlen ? j1 : kvlen - 1;
      int g0 = j0 < 880 ? j0 : wstart + (j0 - 880);
      int g1 = j1 < 880 ? j1 : wstart + (j1 - 880);
      short8 v0 = *(const short8*)(qkv + (long)g0 * 4608 + 3072 + h * 128 + dc * 8);
      short8 v1 = *(const short8*)(qkv + (long)g1 * 4608 + 3072 + h * 128 + dc * 8);
#pragma unroll
      for (int e = 0; e < 8; ++e) {
        int d = dc * 8 + e;
        int byte = d * 128 + kvl * 2;
        byte ^= (((d & 7) ^ ((d >> 3) & 7)) << 4);
        *(unsigned int*)((char*)Vt + byte) =
            (unsigned int)(unsigned short)v0[e] |
            ((unsigned int)(unsigned short)v1[e] << 16);
      }
    }
    __syncthreads();

    // --- S = Q.K^T (log2-domain, scale folded into Q) ---
    f32x4 sv[4];
#pragma unroll
    for (int tt = 0; tt < 4; ++tt) {
      f32x4 a = (f32x4){0.f, 0.f, 0.f, 0.f};
      int kv = tt * 16 + lr;
#pragma unroll
      for (int kk = 0; kk < 4; ++kk) {
        int byte = kv * 256 + kk * 64 + lg * 16;
        byte ^= ((kv & 7) << 4);
        short8 kf = *(const short8*)((const char*)Kl + byte);
        a = MFMA16(qf[kk], kf, a);
      }
      if (t * 64 + tt * 16 + lr >= kvlen)
        a = (f32x4){-1e30f, -1e30f, -1e30f, -1e30f};
      sv[tt] = a;
    }

    // --- online softmax (rows = lg*4+r, cols across 16-lane group) ---
    float alpha[4];
#pragma unroll
    for (int r = 0; r < 4; ++r) {
      float tm = fmaxf(fmaxf(sv[0][r], sv[1][r]), fmaxf(sv[2][r], sv[3][r]));
      tm = fmaxf(tm, __shfl_xor(tm, 1, 64));
      tm = fmaxf(tm, __shfl_xor(tm, 2, 64));
      tm = fmaxf(tm, __shfl_xor(tm, 4, 64));
      tm = fmaxf(tm, __shfl_xor(tm, 8, 64));
      float mn = fmaxf(mrow[r], tm);
      alpha[r] = __builtin_amdgcn_exp2f(mrow[r] - mn);
      float rsum = 0.f;
#pragma unroll
      for (int tt = 0; tt < 4; ++tt) {
        float p = __builtin_amdgcn_exp2f(sv[tt][r] - mn);
        sv[tt][r] = p;
        rsum += p;
      }
      rsum += __shfl_xor(rsum, 1, 64);
      rsum += __shfl_xor(rsum, 2, 64);
      rsum += __shfl_xor(rsum, 4, 64);
      rsum += __shfl_xor(rsum, 8, 64);
      lrow[r] = lrow[r] * alpha[r] + rsum;
      mrow[r] = mn;
    }
#pragma unroll
    for (int dt = 0; dt < 8; ++dt)
#pragma unroll
      for (int r = 0; r < 4; ++r) Oc[dt][r] *= alpha[r];

    // --- P -> LDS (bf16) ---
#pragma unroll
    for (int tt = 0; tt < 4; ++tt)
#pragma unroll
      for (int r = 0; r < 4; ++r) {
        int row = lg * 4 + r, col = tt * 16 + lr;
        int byte = row * 128 + col * 2;
        byte ^= ((row & 7) << 4);
        *(unsigned short*)((char*)&Pl[wave][0] + byte) = f2bf(sv[tt][r]);
      }

    // --- O += P.V ---
    short8 pf[2];
#pragma unroll
    for (int kk = 0; kk < 2; ++kk) {
      int byte = lr * 128 + kk * 64 + lg * 16;
      byte ^= ((lr & 7) << 4);
      pf[kk] = *(const short8*)((const char*)&Pl[wave][0] + byte);
    }
#pragma unroll
    for (int dt = 0; dt < 8; ++dt)
#pragma unroll
      for (int kk = 0; kk < 2; ++kk) {
        int d = dt * 16 + lr;
        int byte = d * 128 + kk * 64 + lg * 16;
        byte ^= (((d & 7) ^ ((d >> 3) & 7)) << 4);
        short8 vf = *(const short8*)((const char*)Vt + byte);
        Oc[dt] = MFMA16(pf[kk], vf, Oc[dt]);
      }
    __syncthreads();
  }

  // --- epilogue ---
#pragma unroll
  for (int r = 0; r < 4; ++r) {
    int row = q0 + wave * 16 + lg * 4 + r;
    if (row < chunk_end) {
      float inv = 1.f / lrow[r];
#pragma unroll
      for (int dt = 0; dt < 8; ++dt)
        ob[(long)row * 1536 + h * 128 + dt * 16 + lr] = f2bf(Oc[dt][r] * inv);
    }
  }
}

// ---------------- launch ----------------
extern "C" void kernel_launch(void* const* d_in, const int* in_sizes, int n_in,
                              void* d_out, int out_size, void* d_ws, size_t ws_size,
                              hipStream_t stream)
{
  const float* x  = (const float*)d_in[0];
  const float* Wq = (const float*)d_in[1];
  const float* bq = (const float*)d_in[2];
  const float* Wk = (const float*)d_in[3];
  const float* bk = (const float*)d_in[4];
  const float* Wv = (const float*)d_in[5];
  const float* bv = (const float*)d_in[6];
  const float* Wo = (const float*)d_in[7];
  const float* bo = (const float*)d_in[8];
  const float* gq = (const float*)d_in[9];
  const float* gk = (const float*)d_in[10];
  const float* fc = (const float*)d_in[11];
  const float* fs = (const float*)d_in[12];

  char* ws = (char*)d_ws;
  unsigned short* xb   = (unsigned short*)(ws);               // 21,626,880 B
  unsigned short* wcat = (unsigned short*)(ws + 21626880);    // 14,155,776 B (Wq|Wk|Wv bf16)
  unsigned short* wob  = (unsigned short*)(ws + 35782656);    //  4,718,592 B
  float*          bcat = (float*)(ws + 40501248);             //     18,432 B
  unsigned short* qkv  = (unsigned short*)(ws + 40519680);    // 64,880,640 B [L][4608]
  unsigned short* obuf = (unsigned short*)(ws + 105400320);   // 21,626,880 B  (end ~127 MB)

  cvt_f32_bf16<<<2048, 256, 0, stream>>>(x,  xb,   10813440 / 4);
  cvt_f32_bf16<<<1024, 256, 0, stream>>>(Wq, wcat,            2359296 / 4);
  cvt_f32_bf16<<<1024, 256, 0, stream>>>(Wk, wcat + 2359296,  2359296 / 4);
  cvt_f32_bf16<<<1024, 256, 0, stream>>>(Wv, wcat + 4718592,  2359296 / 4);
  cvt_f32_bf16<<<1024, 256, 0, stream>>>(Wo, wob,             2359296 / 4);
  hipMemcpyAsync(bcat,        bq, 1536 * 4, hipMemcpyDeviceToDevice, stream);
  hipMemcpyAsync(bcat + 1536, bk, 1536 * 4, hipMemcpyDeviceToDevice, stream);
  hipMemcpyAsync(bcat + 3072, bv, 1536 * 4, hipMemcpyDeviceToDevice, stream);

  // QKV projection: [7040x4608] = xb . wcat^T + bcat
  gemm_bt<0><<<dim3(36, 55), 256, 0, stream>>>(xb, wcat, bcat, qkv, nullptr, 1536, 4608);

  const float qsc = (float)(1.4426950408889634 / sqrt(128.0)); // softmax scale * log2(e)
  normrope<<<7040, 256, 0, stream>>>(qkv, gq, fc, fs, 0,    qsc);
  normrope<<<7040, 256, 0, stream>>>(qkv, gk, fc, fs, 1536, 1.0f);

  attn_kern<<<dim3(28, 4, 12), 256, 0, stream>>>(qkv, obuf);

  // output projection: d_out = obuf . Wo^T + bo  (f32)
  gemm_bt<1><<<dim3(12, 55), 256, 0, stream>>>(obuf, wob, bo, nullptr, (float*)d_out, 1536, 1536);
}

// Round 2
// 550.227 us; speedup vs baseline: 1.0902x; 1.0902x over previous
//
#include <hip/hip_runtime.h>
#include <math.h>

typedef __attribute__((ext_vector_type(8))) short short8;
typedef __attribute__((ext_vector_type(4))) float f32x4;
typedef __attribute__((ext_vector_type(4))) float f4;
typedef __attribute__((ext_vector_type(4))) unsigned short us4;

#define MFMA16(a,b,c) __builtin_amdgcn_mfma_f32_16x16x32_bf16(a,b,c,0,0,0)

__device__ __forceinline__ unsigned short f2bf(float f) {
  unsigned int u = __float_as_uint(f);
  u = (u + 0x7FFFu + ((u >> 16) & 1u)) >> 16;   // RNE
  return (unsigned short)u;
}
__device__ __forceinline__ float bf2f(unsigned short b) {
  return __uint_as_float(((unsigned int)b) << 16);
}

typedef const __attribute__((address_space(1))) unsigned int* gas_t;
typedef __attribute__((address_space(3))) unsigned int* las_t;
__device__ __forceinline__ void gl16(const void* g, void* l) {
  __builtin_amdgcn_global_load_lds((gas_t)g, (las_t)l, 16, 0, 0);
}

// ---------------- f32 -> bf16 convert ----------------
__global__ void cvt_f32_bf16(const float* __restrict__ in,
                             unsigned short* __restrict__ out, int n4) {
  int i = blockIdx.x * blockDim.x + threadIdx.x;
  const int stride = gridDim.x * blockDim.x;
  for (; i < n4; i += stride) {
    f4 v = ((const f4*)in)[i];
    us4 o;
    o[0] = f2bf(v[0]); o[1] = f2bf(v[1]); o[2] = f2bf(v[2]); o[3] = f2bf(v[3]);
    ((us4*)out)[i] = o;
  }
}

// ---------------- NT GEMM: out[m][n] = sum_k A[m][k]*B[n][k] + bias[n] ----------------
template<int F32OUT>
__global__ __launch_bounds__(256)
void gemm_bt(const unsigned short* __restrict__ A,
             const unsigned short* __restrict__ B,
             const float* __restrict__ bias,
             unsigned short* __restrict__ obf,
             float* __restrict__ of32,
             int K, int ldo)
{
  const int tid = threadIdx.x;
  const int wave = tid >> 6, lane = tid & 63, lg = lane >> 4, lr = lane & 15;
  const int wr = wave >> 1, wc = wave & 1;
  const int m0 = blockIdx.y * 128, n0 = blockIdx.x * 128;

  __shared__ __align__(16) unsigned short Al[128 * 32];
  __shared__ __align__(16) unsigned short Bl[128 * 32];

  f32x4 acc[4][4];
#pragma unroll
  for (int m = 0; m < 4; ++m)
#pragma unroll
    for (int n = 0; n < 4; ++n) acc[m][n] = (f32x4){0.f, 0.f, 0.f, 0.f};

  const int r0 = tid >> 2, r1 = (tid + 256) >> 2;
  const int c0 = (tid & 3) * 8;
  const long arow0 = (long)(m0 + r0) * K, arow1 = (long)(m0 + r1) * K;
  const long brow0 = (long)(n0 + r0) * K, brow1 = (long)(n0 + r1) * K;

  for (int k0 = 0; k0 < K; k0 += 32) {
    gl16(A + arow0 + k0 + c0, (char*)Al + tid * 16);
    gl16(A + arow1 + k0 + c0, (char*)Al + (tid + 256) * 16);
    gl16(B + brow0 + k0 + c0, (char*)Bl + tid * 16);
    gl16(B + brow1 + k0 + c0, (char*)Bl + (tid + 256) * 16);
    __syncthreads();
    short8 af[4], bf[4];
#pragma unroll
    for (int m = 0; m < 4; ++m)
      af[m] = *(const short8*)(Al + (wr * 64 + m * 16 + lr) * 32 + lg * 8);
#pragma unroll
    for (int n = 0; n < 4; ++n)
      bf[n] = *(const short8*)(Bl + (wc * 64 + n * 16 + lr) * 32 + lg * 8);
#pragma unroll
    for (int m = 0; m < 4; ++m)
#pragma unroll
      for (int n = 0; n < 4; ++n)
        acc[m][n] = MFMA16(af[m], bf[n], acc[m][n]);
    __syncthreads();
  }

#pragma unroll
  for (int n = 0; n < 4; ++n) {
    const int col = n0 + wc * 64 + n * 16 + lr;
    const float bs = bias[col];
#pragma unroll
    for (int m = 0; m < 4; ++m) {
      const int row = m0 + wr * 64 + m * 16 + lg * 4;
#pragma unroll
      for (int r = 0; r < 4; ++r) {
        float v = acc[m][n][r] + bs;
        if (F32OUT) of32[(long)(row + r) * ldo + col] = v;
        else        obf[(long)(row + r) * ldo + col] = f2bf(v);
      }
    }
  }
}

// ---------------- fused RMSNorm + RoPE ----------------
__global__ __launch_bounds__(256)
void normrope(unsigned short* __restrict__ qkv, const float* __restrict__ g,
              const float* __restrict__ fc, const float* __restrict__ fs,
              int colOff, float oscale)
{
  const int l = blockIdx.x, tid = threadIdx.x;
  __shared__ float rowbuf[1536];
  __shared__ float sred[4];
  unsigned short* rp = qkv + (long)l * 4608 + colOff;

  float ss = 0.f;
  if (tid < 192) {
    short8 v = *(const short8*)(rp + tid * 8);
#pragma unroll
    for (int e = 0; e < 8; ++e) {
      float f = bf2f((unsigned short)v[e]);
      rowbuf[tid * 8 + e] = f;
      ss += f * f;
    }
  }
#pragma unroll
  for (int m = 32; m; m >>= 1) ss += __shfl_xor(ss, m, 64);
  if ((tid & 63) == 0) sred[tid >> 6] = ss;
  __syncthreads();
  const float rs = rsqrtf((sred[0] + sred[1] + sred[2] + sred[3]) * (1.f / 1536.f) + 1e-6f);

  const int f_ = l / 880, rem = l % 880, h_ = rem / 40, w_ = rem % 40;
#pragma unroll
  for (int j = 0; j < 3; ++j) {
    int p = tid + j * 256;
    int head = p >> 6, c = p & 63;
    int e = head * 128 + 2 * c;
    int tr = (c < 22) ? f_ : ((c < 43) ? h_ : w_);
    float co = fc[tr * 64 + c], si = fs[tr * 64 + c];
    float xr = rowbuf[e] * rs * g[e];
    float xi = rowbuf[e + 1] * rs * g[e + 1];
    float yr = (xr * co - xi * si) * oscale;
    float yi = (xr * si + xi * co) * oscale;
    unsigned int pk = (unsigned int)f2bf(yr) | ((unsigned int)f2bf(yi) << 16);
    *(unsigned int*)(rp + e) = pk;
  }
}

// ---------------- attention staging helpers ----------------
__device__ __forceinline__ void issueK(const unsigned short* __restrict__ qkv,
                                       int h, int t, int kvlen, int woff, int tid,
                                       unsigned short* Kbuf)
{
#pragma unroll
  for (int i = 0; i < 4; ++i) {
    int s = i * 256 + tid;
    int kvl = s >> 4;
    int dc = (s & 15) ^ (kvl & 7);
    int j = t * 64 + kvl; j = j < kvlen ? j : kvlen - 1;
    int gk = j + (j >= 880 ? woff : 0);
    gl16(qkv + (long)gk * 4608 + 1536 + h * 128 + dc * 8, (char*)Kbuf + s * 16);
  }
}

__device__ __forceinline__ void loadV(const unsigned short* __restrict__ qkv,
                                      int h, int t, int kvlen, int woff, int tid,
                                      short8 vp[2][2])
{
#pragma unroll
  for (int i = 0; i < 2; ++i) {
    int task = i * 256 + tid;
    int dc = task & 15, kp = task >> 4;
    int kvl = kp * 2;
    int j0 = t * 64 + kvl, j1 = j0 + 1;
    j0 = j0 < kvlen ? j0 : kvlen - 1;
    j1 = j1 < kvlen ? j1 : kvlen - 1;
    int g0 = j0 + (j0 >= 880 ? woff : 0);
    int g1 = j1 + (j1 >= 880 ? woff : 0);
    vp[i][0] = *(const short8*)(qkv + (long)g0 * 4608 + 3072 + h * 128 + dc * 8);
    vp[i][1] = *(const short8*)(qkv + (long)g1 * 4608 + 3072 + h * 128 + dc * 8);
  }
}

__device__ __forceinline__ void writeV(int tid, short8 vp[2][2], unsigned short* Vt)
{
#pragma unroll
  for (int i = 0; i < 2; ++i) {
    int task = i * 256 + tid;
    int dc = task & 15, kp = task >> 4;
    int kvl = kp * 2;
#pragma unroll
    for (int e = 0; e < 8; ++e) {
      int d = dc * 8 + e;
      int byte = d * 128 + kvl * 2;
      byte ^= (((d & 7) ^ ((d >> 3) & 7)) << 4);
      *(unsigned int*)((char*)Vt + byte) =
          (unsigned int)(unsigned short)vp[i][0][e] |
          ((unsigned int)(unsigned short)vp[i][1][e] << 16);
    }
  }
}

// ---------------- chunked sink+window attention ----------------
// grid (28 qtiles, 4 chunks, 12 heads); 4 waves x 16 q-rows; KV tile 64.
// Depth-1 pipeline: prefetch next K (gl16, dbuf) + next V (regs) before compute.
__global__ __launch_bounds__(256, 2)
void attn_kern(const unsigned short* __restrict__ qkv,
               unsigned short* __restrict__ ob)
{
  const int qt = blockIdx.x, ci = blockIdx.y, h = blockIdx.z;
  const int tid = threadIdx.x, wave = tid >> 6, lane = tid & 63;
  const int lg = lane >> 4, lr = lane & 15;
  const int chunk_start = ci * 1760, chunk_end = chunk_start + 1760;
  const int wstart = (ci == 0) ? 880 : ci * 1760;
  const int woff = wstart - 880;                    // 0 for chunk 0
  const int kvlen = 880 + (chunk_end - wstart);     // 1760 or 2640
  const int q0 = chunk_start + qt * 64;

  __shared__ __align__(16) unsigned short Kl[2][64 * 128]; // dbuf, swz ^((kv&7)<<4)
  __shared__ __align__(16) unsigned short Vt[128 * 64];    // [d][kv], swz ^(((d&7)^((d>>3)&7))<<4)
  __shared__ __align__(16) unsigned short Pl[4][16 * 64];  // per-wave P, swz ^((row&7)<<4)

  int qr = q0 + wave * 16 + lr;
  if (qr >= chunk_end) qr = chunk_end - 1;
  const unsigned short* qp = qkv + (long)qr * 4608 + h * 128;
  short8 qf[4];
#pragma unroll
  for (int kk = 0; kk < 4; ++kk) qf[kk] = *(const short8*)(qp + kk * 32 + lg * 8);

  f32x4 Oc[8];
#pragma unroll
  for (int i = 0; i < 8; ++i) Oc[i] = (f32x4){0.f, 0.f, 0.f, 0.f};
  float mrow[4] = {-1e30f, -1e30f, -1e30f, -1e30f};
  float lrow[4] = {0.f, 0.f, 0.f, 0.f};

  const int nt = (kvlen + 63) >> 6;

  // prologue: stage tile 0
  short8 vp[2][2];
  issueK(qkv, h, 0, kvlen, woff, tid, &Kl[0][0]);
  loadV(qkv, h, 0, kvlen, woff, tid, vp);
  writeV(tid, vp, Vt);          // compiler inserts vmcnt wait on vp
  __syncthreads();              // drains gl16 (vmcnt 0) + lds writes

  for (int t = 0; t < nt; ++t) {
    const int cur = t & 1;
    const bool pf = (t + 1 < nt);
    if (pf) {
      issueK(qkv, h, t + 1, kvlen, woff, tid, &Kl[cur ^ 1][0]);
      loadV(qkv, h, t + 1, kvlen, woff, tid, vp);
    }

    // --- S = Q.K^T (log2 domain; scale folded into Q) ---
    f32x4 sv[4];
    __builtin_amdgcn_s_setprio(1);
#pragma unroll
    for (int tt = 0; tt < 4; ++tt) {
      f32x4 a = (f32x4){0.f, 0.f, 0.f, 0.f};
      int kv = tt * 16 + lr;
#pragma unroll
      for (int kk = 0; kk < 4; ++kk) {
        int byte = kv * 256 + kk * 64 + lg * 16;
        byte ^= ((kv & 7) << 4);
        short8 kf = *(const short8*)((const char*)&Kl[cur][0] + byte);
        a = MFMA16(qf[kk], kf, a);
      }
      sv[tt] = a;
    }
    __builtin_amdgcn_s_setprio(0);
    if (t * 64 + 64 > kvlen) {       // uniform: tail tile only
#pragma unroll
      for (int tt = 0; tt < 4; ++tt)
        if (t * 64 + tt * 16 + lr >= kvlen)
          sv[tt] = (f32x4){-1e30f, -1e30f, -1e30f, -1e30f};
    }

    // --- online softmax ---
    float alpha[4];
#pragma unroll
    for (int r = 0; r < 4; ++r) {
      float tm = fmaxf(fmaxf(sv[0][r], sv[1][r]), fmaxf(sv[2][r], sv[3][r]));
      tm = fmaxf(tm, __shfl_xor(tm, 1, 64));
      tm = fmaxf(tm, __shfl_xor(tm, 2, 64));
      tm = fmaxf(tm, __shfl_xor(tm, 4, 64));
      tm = fmaxf(tm, __shfl_xor(tm, 8, 64));
      float mn = fmaxf(mrow[r], tm);
      alpha[r] = __builtin_amdgcn_exp2f(mrow[r] - mn);
      float rsum = 0.f;
#pragma unroll
      for (int tt = 0; tt < 4; ++tt) {
        float p = __builtin_amdgcn_exp2f(sv[tt][r] - mn);
        sv[tt][r] = p;
        rsum += p;
      }
      rsum += __shfl_xor(rsum, 1, 64);
      rsum += __shfl_xor(rsum, 2, 64);
      rsum += __shfl_xor(rsum, 4, 64);
      rsum += __shfl_xor(rsum, 8, 64);
      lrow[r] = lrow[r] * alpha[r] + rsum;
      mrow[r] = mn;
    }

    // --- P -> LDS first (hide write latency under rescale) ---
#pragma unroll
    for (int tt = 0; tt < 4; ++tt)
#pragma unroll
      for (int r = 0; r < 4; ++r) {
        int row = lg * 4 + r, col = tt * 16 + lr;
        int byte = row * 128 + col * 2;
        byte ^= ((row & 7) << 4);
        *(unsigned short*)((char*)&Pl[wave][0] + byte) = f2bf(sv[tt][r]);
      }

    // --- O rescale ---
#pragma unroll
    for (int dt = 0; dt < 8; ++dt)
#pragma unroll
      for (int r = 0; r < 4; ++r) Oc[dt][r] *= alpha[r];

    // --- O += P.V ---
    short8 pfg[2];
#pragma unroll
    for (int kk = 0; kk < 2; ++kk) {
      int byte = lr * 128 + kk * 64 + lg * 16;
      byte ^= ((lr & 7) << 4);
      pfg[kk] = *(const short8*)((const char*)&Pl[wave][0] + byte);
    }
    __builtin_amdgcn_s_setprio(1);
#pragma unroll
    for (int dt = 0; dt < 8; ++dt)
#pragma unroll
      for (int kk = 0; kk < 2; ++kk) {
        int d = dt * 16 + lr;
        int byte = d * 128 + kk * 64 + lg * 16;
        byte ^= (((d & 7) ^ ((d >> 3) & 7)) << 4);
        short8 vf = *(const short8*)((const char*)Vt + byte);
        Oc[dt] = MFMA16(pfg[kk], vf, Oc[dt]);
      }
    __builtin_amdgcn_s_setprio(0);

    __syncthreads();             // done reading Vt & Kl[cur]; drains prefetches
    if (pf) writeV(tid, vp, Vt);
    __syncthreads();             // Vt + Kl[cur^1] ready
  }

  // --- epilogue ---
#pragma unroll
  for (int r = 0; r < 4; ++r) {
    int row = q0 + wave * 16 + lg * 4 + r;
    if (row < chunk_end) {
      float inv = 1.f / lrow[r];
#pragma unroll
      for (int dt = 0; dt < 8; ++dt)
        ob[(long)row * 1536 + h * 128 + dt * 16 + lr] = f2bf(Oc[dt][r] * inv);
    }
  }
}

// ---------------- launch ----------------
extern "C" void kernel_launch(void* const* d_in, const int* in_sizes, int n_in,
                              void* d_out, int out_size, void* d_ws, size_t ws_size,
                              hipStream_t stream)
{
  const float* x  = (const float*)d_in[0];
  const float* Wq = (const float*)d_in[1];
  const float* bq = (const float*)d_in[2];
  const float* Wk = (const float*)d_in[3];
  const float* bk = (const float*)d_in[4];
  const float* Wv = (const float*)d_in[5];
  const float* bv = (const float*)d_in[6];
  const float* Wo = (const float*)d_in[7];
  const float* bo = (const float*)d_in[8];
  const float* gq = (const float*)d_in[9];
  const float* gk = (const float*)d_in[10];
  const float* fc = (const float*)d_in[11];
  const float* fs = (const float*)d_in[12];

  char* ws = (char*)d_ws;
  unsigned short* xb   = (unsigned short*)(ws);
  unsigned short* wcat = (unsigned short*)(ws + 21626880);
  unsigned short* wob  = (unsigned short*)(ws + 35782656);
  float*          bcat = (float*)(ws + 40501248);
  unsigned short* qkv  = (unsigned short*)(ws + 40519680);
  unsigned short* obuf = (unsigned short*)(ws + 105400320);

  cvt_f32_bf16<<<2048, 256, 0, stream>>>(x,  xb,   10813440 / 4);
  cvt_f32_bf16<<<1024, 256, 0, stream>>>(Wq, wcat,            2359296 / 4);
  cvt_f32_bf16<<<1024, 256, 0, stream>>>(Wk, wcat + 2359296,  2359296 / 4);
  cvt_f32_bf16<<<1024, 256, 0, stream>>>(Wv, wcat + 4718592,  2359296 / 4);
  cvt_f32_bf16<<<1024, 256, 0, stream>>>(Wo, wob,             2359296 / 4);
  hipMemcpyAsync(bcat,        bq, 1536 * 4, hipMemcpyDeviceToDevice, stream);
  hipMemcpyAsync(bcat + 1536, bk, 1536 * 4, hipMemcpyDeviceToDevice, stream);
  hipMemcpyAsync(bcat + 3072, bv, 1536 * 4, hipMemcpyDeviceToDevice, stream);

  gemm_bt<0><<<dim3(36, 55), 256, 0, stream>>>(xb, wcat, bcat, qkv, nullptr, 1536, 4608);

  const float qsc = (float)(1.4426950408889634 / sqrt(128.0));
  normrope<<<7040, 256, 0, stream>>>(qkv, gq, fc, fs, 0,    qsc);
  normrope<<<7040, 256, 0, stream>>>(qkv, gk, fc, fs, 1536, 1.0f);

  attn_kern<<<dim3(28, 4, 12), 256, 0, stream>>>(qkv, obuf);

  gemm_bt<1><<<dim3(12, 55), 256, 0, stream>>>(obuf, wob, bo, nullptr, (float*)d_out, 1536, 1536);
}

// Round 3
// 476.104 us; speedup vs baseline: 1.2600x; 1.1557x over previous
//
#include <hip/hip_runtime.h>
#include <math.h>

typedef __attribute__((ext_vector_type(8))) short short8;
typedef __attribute__((ext_vector_type(4))) float f32x4;
typedef __attribute__((ext_vector_type(16))) float f32x16;
typedef __attribute__((ext_vector_type(4))) float f4;
typedef __attribute__((ext_vector_type(4))) unsigned short us4;
typedef __attribute__((ext_vector_type(2))) unsigned int u32x2;

#define MFMA16(a,b,c) __builtin_amdgcn_mfma_f32_16x16x32_bf16(a,b,c,0,0,0)
#define MFMA32(a,b,c) __builtin_amdgcn_mfma_f32_32x32x16_bf16(a,b,c,0,0,0)

__device__ __forceinline__ unsigned short f2bf(float f) {
  unsigned int u = __float_as_uint(f);
  u = (u + 0x7FFFu + ((u >> 16) & 1u)) >> 16;   // RNE
  return (unsigned short)u;
}
__device__ __forceinline__ float bf2f(unsigned short b) {
  return __uint_as_float(((unsigned int)b) << 16);
}

typedef const __attribute__((address_space(1))) unsigned int* gas_t;
typedef __attribute__((address_space(3))) unsigned int* las_t;
__device__ __forceinline__ void gl16(const void* g, void* l) {
  __builtin_amdgcn_global_load_lds((gas_t)g, (las_t)l, 16, 0, 0);
}

// ---------------- f32 -> bf16 convert ----------------
__global__ void cvt_f32_bf16(const float* __restrict__ in,
                             unsigned short* __restrict__ out, int n4) {
  int i = blockIdx.x * blockDim.x + threadIdx.x;
  const int stride = gridDim.x * blockDim.x;
  for (; i < n4; i += stride) {
    f4 v = ((const f4*)in)[i];
    us4 o;
    o[0] = f2bf(v[0]); o[1] = f2bf(v[1]); o[2] = f2bf(v[2]); o[3] = f2bf(v[3]);
    ((us4*)out)[i] = o;
  }
}

// ---------------- NT GEMM: out[m][n] = sum_k A[m][k]*B[n][k] + bias[n] ----------------
template<int F32OUT>
__global__ __launch_bounds__(256)
void gemm_bt(const unsigned short* __restrict__ A,
             const unsigned short* __restrict__ B,
             const float* __restrict__ bias,
             unsigned short* __restrict__ obf,
             float* __restrict__ of32,
             int K, int ldo)
{
  const int tid = threadIdx.x;
  const int wave = tid >> 6, lane = tid & 63, lg = lane >> 4, lr = lane & 15;
  const int wr = wave >> 1, wc = wave & 1;
  const int m0 = blockIdx.y * 128, n0 = blockIdx.x * 128;

  __shared__ __align__(16) unsigned short Al[128 * 32];
  __shared__ __align__(16) unsigned short Bl[128 * 32];

  f32x4 acc[4][4];
#pragma unroll
  for (int m = 0; m < 4; ++m)
#pragma unroll
    for (int n = 0; n < 4; ++n) acc[m][n] = (f32x4){0.f, 0.f, 0.f, 0.f};

  const int r0 = tid >> 2, r1 = (tid + 256) >> 2;
  const int c0 = (tid & 3) * 8;
  const long arow0 = (long)(m0 + r0) * K, arow1 = (long)(m0 + r1) * K;
  const long brow0 = (long)(n0 + r0) * K, brow1 = (long)(n0 + r1) * K;

  for (int k0 = 0; k0 < K; k0 += 32) {
    gl16(A + arow0 + k0 + c0, (char*)Al + tid * 16);
    gl16(A + arow1 + k0 + c0, (char*)Al + (tid + 256) * 16);
    gl16(B + brow0 + k0 + c0, (char*)Bl + tid * 16);
    gl16(B + brow1 + k0 + c0, (char*)Bl + (tid + 256) * 16);
    __syncthreads();
    short8 af[4], bf[4];
#pragma unroll
    for (int m = 0; m < 4; ++m)
      af[m] = *(const short8*)(Al + (wr * 64 + m * 16 + lr) * 32 + lg * 8);
#pragma unroll
    for (int n = 0; n < 4; ++n)
      bf[n] = *(const short8*)(Bl + (wc * 64 + n * 16 + lr) * 32 + lg * 8);
#pragma unroll
    for (int m = 0; m < 4; ++m)
#pragma unroll
      for (int n = 0; n < 4; ++n)
        acc[m][n] = MFMA16(af[m], bf[n], acc[m][n]);
    __syncthreads();
  }

#pragma unroll
  for (int n = 0; n < 4; ++n) {
    const int col = n0 + wc * 64 + n * 16 + lr;
    const float bs = bias[col];
#pragma unroll
    for (int m = 0; m < 4; ++m) {
      const int row = m0 + wr * 64 + m * 16 + lg * 4;
#pragma unroll
      for (int r = 0; r < 4; ++r) {
        float v = acc[m][n][r] + bs;
        if (F32OUT) of32[(long)(row + r) * ldo + col] = v;
        else        obf[(long)(row + r) * ldo + col] = f2bf(v);
      }
    }
  }
}

// ---------------- fused RMSNorm + RoPE ----------------
__global__ __launch_bounds__(256)
void normrope(unsigned short* __restrict__ qkv, const float* __restrict__ g,
              const float* __restrict__ fc, const float* __restrict__ fs,
              int colOff, float oscale)
{
  const int l = blockIdx.x, tid = threadIdx.x;
  __shared__ float rowbuf[1536];
  __shared__ float sred[4];
  unsigned short* rp = qkv + (long)l * 4608 + colOff;

  float ss = 0.f;
  if (tid < 192) {
    short8 v = *(const short8*)(rp + tid * 8);
#pragma unroll
    for (int e = 0; e < 8; ++e) {
      float f = bf2f((unsigned short)v[e]);
      rowbuf[tid * 8 + e] = f;
      ss += f * f;
    }
  }
#pragma unroll
  for (int m = 32; m; m >>= 1) ss += __shfl_xor(ss, m, 64);
  if ((tid & 63) == 0) sred[tid >> 6] = ss;
  __syncthreads();
  const float rs = rsqrtf((sred[0] + sred[1] + sred[2] + sred[3]) * (1.f / 1536.f) + 1e-6f);

  const int f_ = l / 880, rem = l % 880, h_ = rem / 40, w_ = rem % 40;
#pragma unroll
  for (int j = 0; j < 3; ++j) {
    int p = tid + j * 256;
    int head = p >> 6, c = p & 63;
    int e = head * 128 + 2 * c;
    int tr = (c < 22) ? f_ : ((c < 43) ? h_ : w_);
    float co = fc[tr * 64 + c], si = fs[tr * 64 + c];
    float xr = rowbuf[e] * rs * g[e];
    float xi = rowbuf[e + 1] * rs * g[e + 1];
    float yr = (xr * co - xi * si) * oscale;
    float yi = (xr * si + xi * co) * oscale;
    unsigned int pk = (unsigned int)f2bf(yr) | ((unsigned int)f2bf(yi) << 16);
    *(unsigned int*)(rp + e) = pk;
  }
}

// ---------------- attention staging helpers (256 threads) ----------------
// K tile: Kl[kv][128d], linear dest, inverse-swizzled source col -> reads use ^((kv&7)<<4)
__device__ __forceinline__ void issueK(const unsigned short* __restrict__ qkv,
                                       int h, int t, int kvlen, int woff, int tid,
                                       unsigned short* Kbuf)
{
#pragma unroll
  for (int i = 0; i < 4; ++i) {
    int s = i * 256 + tid;
    int kvl = s >> 4;
    int dc = (s & 15) ^ (kvl & 7);
    int j = t * 64 + kvl; j = j < kvlen ? j : kvlen - 1;
    int gk = j + (j >= 880 ? woff : 0);
    gl16(qkv + (long)gk * 4608 + 1536 + h * 128 + dc * 8, (char*)Kbuf + s * 16);
  }
}

__device__ __forceinline__ void loadV(const unsigned short* __restrict__ qkv,
                                      int h, int t, int kvlen, int woff, int tid,
                                      short8 vp[2][2])
{
#pragma unroll
  for (int i = 0; i < 2; ++i) {
    int task = i * 256 + tid;
    int dc = task & 15, kp = task >> 4;
    int kvl = kp * 2;
    int j0 = t * 64 + kvl, j1 = j0 + 1;
    j0 = j0 < kvlen ? j0 : kvlen - 1;
    j1 = j1 < kvlen ? j1 : kvlen - 1;
    int g0 = j0 + (j0 >= 880 ? woff : 0);
    int g1 = j1 + (j1 >= 880 ? woff : 0);
    vp[i][0] = *(const short8*)(qkv + (long)g0 * 4608 + 3072 + h * 128 + dc * 8);
    vp[i][1] = *(const short8*)(qkv + (long)g1 * 4608 + 3072 + h * 128 + dc * 8);
  }
}

// V^T tile: Vt[d][64kv], swizzle byte ^= ((d&7)^((d>>3)&7))<<4  (write 2-way-free, read 8/slot even)
__device__ __forceinline__ void writeV(int tid, short8 vp[2][2], unsigned short* Vt)
{
#pragma unroll
  for (int i = 0; i < 2; ++i) {
    int task = i * 256 + tid;
    int dc = task & 15, kp = task >> 4;
    int kvl = kp * 2;
#pragma unroll
    for (int e = 0; e < 8; ++e) {
      int d = dc * 8 + e;
      int byte = d * 128 + kvl * 2;
      byte ^= (((d & 7) ^ ((d >> 3) & 7)) << 4);
      *(unsigned int*)((char*)Vt + byte) =
          (unsigned int)(unsigned short)vp[i][0][e] |
          ((unsigned int)(unsigned short)vp[i][1][e] << 16);
    }
  }
}

// ---------------- chunked sink+window attention, 32x32 swapped-operand ----------------
// grid (14 qtiles, 4 chunks, 12 heads); 4 waves x 32 q-rows = 128 q/block; KV tile 64.
// S^T = mfma32(K, Q): lane owns q=lane&31; 32 P-values in-register -> in-lane softmax.
__global__ __launch_bounds__(256, 2)
void attn_kern(const unsigned short* __restrict__ qkv,
               unsigned short* __restrict__ ob)
{
  const int qt = blockIdx.x, ci = blockIdx.y, h = blockIdx.z;
  const int tid = threadIdx.x, wave = tid >> 6, lane = tid & 63;
  const int l31 = lane & 31, hh = lane >> 5;
  const int chunk_start = ci * 1760, chunk_end = chunk_start + 1760;
  const int wstart = (ci == 0) ? 880 : ci * 1760;
  const int woff = wstart - 880;
  const int kvlen = 880 + (chunk_end - wstart);     // 1760 or 2640
  const int q0 = chunk_start + qt * 128;

  __shared__ __align__(16) unsigned short Kl[2][64 * 128];
  __shared__ __align__(16) unsigned short Vt[128 * 64];

  // Q fragments (B-operand): lane: q = q0+wave*32+l31, k = st*16 + hh*8 + j
  int qr = q0 + wave * 32 + l31;
  if (qr >= chunk_end) qr = chunk_end - 1;
  const unsigned short* qp = qkv + (long)qr * 4608 + h * 128;
  short8 qf[8];
#pragma unroll
  for (int st = 0; st < 8; ++st) qf[st] = *(const short8*)(qp + st * 16 + hh * 8);

  f32x16 Oc[4];
#pragma unroll
  for (int i = 0; i < 4; ++i)
#pragma unroll
    for (int j = 0; j < 16; ++j) Oc[i][j] = 0.f;
  float m_run = -1e30f, l_run = 0.f;

  const int nt = (kvlen + 63) >> 6;
  short8 vp[2][2];
  issueK(qkv, h, 0, kvlen, woff, tid, &Kl[0][0]);
  loadV(qkv, h, 0, kvlen, woff, tid, vp);
  writeV(tid, vp, Vt);
  __syncthreads();

  for (int t = 0; t < nt; ++t) {
    const int cur = t & 1;
    const bool pf = (t + 1 < nt);
    if (pf) {
      issueK(qkv, h, t + 1, kvlen, woff, tid, &Kl[cur ^ 1][0]);
      loadV(qkv, h, t + 1, kvlen, woff, tid, vp);
    }

    // --- S^T = K . Q (two kv-subtiles of 32) ---
    f32x16 s0, s1;
#pragma unroll
    for (int j = 0; j < 16; ++j) { s0[j] = 0.f; s1[j] = 0.f; }
    __builtin_amdgcn_s_setprio(1);
#pragma unroll
    for (int st = 0; st < 8; ++st) {
      int off = 32 * st + 16 * hh;
      int b0 = l31 * 256 + (off ^ ((l31 & 7) << 4));
      short8 k0 = *(const short8*)((const char*)&Kl[cur][0] + b0);
      s0 = MFMA32(k0, qf[st], s0);
      int b1 = (32 + l31) * 256 + (off ^ ((l31 & 7) << 4));
      short8 k1 = *(const short8*)((const char*)&Kl[cur][0] + b1);
      s1 = MFMA32(k1, qf[st], s1);
    }
    __builtin_amdgcn_s_setprio(0);

    // --- tail mask (uniform branch) ---
    if (t * 64 + 64 > kvlen) {
#pragma unroll
      for (int r = 0; r < 16; ++r) {
        int kv0 = t * 64 + (r & 3) + 8 * (r >> 2) + 4 * hh;
        if (kv0 >= kvlen)      s0[r] = -1e30f;
        if (kv0 + 32 >= kvlen) s1[r] = -1e30f;
      }
    }

    // --- in-register online softmax (lane owns q = l31; halves exchange once) ---
    float pm = s0[0];
#pragma unroll
    for (int r = 1; r < 16; ++r) pm = fmaxf(pm, s0[r]);
#pragma unroll
    for (int r = 0; r < 16; ++r) pm = fmaxf(pm, s1[r]);
    pm = fmaxf(pm, __shfl_xor(pm, 32, 64));
    float mn = fmaxf(m_run, pm);
    float al = __builtin_amdgcn_exp2f(m_run - mn);
    float sum = 0.f;
#pragma unroll
    for (int r = 0; r < 16; ++r) {
      s0[r] = __builtin_amdgcn_exp2f(s0[r] - mn); sum += s0[r];
      s1[r] = __builtin_amdgcn_exp2f(s1[r] - mn); sum += s1[r];
    }
    sum += __shfl_xor(sum, 32, 64);
    l_run = l_run * al + sum;
    m_run = mn;

    // --- pack P to bf16 words: w0/w1[m] = {p[2m], p[2m+1]} ---
    unsigned int w0[8], w1[8];
#pragma unroll
    for (int m = 0; m < 8; ++m) {
      w0[m] = (unsigned int)f2bf(s0[2 * m]) | ((unsigned int)f2bf(s0[2 * m + 1]) << 16);
      w1[m] = (unsigned int)f2bf(s1[2 * m]) | ((unsigned int)f2bf(s1[2 * m + 1]) << 16);
    }

    // --- O rescale ---
#pragma unroll
    for (int i = 0; i < 4; ++i)
#pragma unroll
      for (int j = 0; j < 16; ++j) Oc[i][j] *= al;

    // --- O^T += V^T . P^T : 4 kv-steps x 4 d-tiles ---
    __builtin_amdgcn_s_setprio(1);
#pragma unroll
    for (int s = 0; s < 4; ++s) {
      const unsigned int* w = (s < 2) ? w0 : w1;
      const int lo4 = (s & 1) * 4;
      unsigned int x0 = __shfl_xor(w[lo4 + 2], 32, 64);
      unsigned int x1 = __shfl_xor(w[lo4 + 3], 32, 64);
      unsigned int y0 = __shfl_xor(w[lo4],     32, 64);
      unsigned int y1 = __shfl_xor(w[lo4 + 1], 32, 64);
      unsigned int fw[4];
      fw[0] = hh ? x0 : w[lo4];
      fw[1] = hh ? x1 : w[lo4 + 1];
      fw[2] = hh ? w[lo4 + 2] : y0;
      fw[3] = hh ? w[lo4 + 3] : y1;
      short8 pb;
#pragma unroll
      for (int m = 0; m < 4; ++m) {
        pb[2 * m]     = (short)(fw[m] & 0xFFFF);
        pb[2 * m + 1] = (short)(fw[m] >> 16);
      }
#pragma unroll
      for (int dt = 0; dt < 4; ++dt) {
        int d = dt * 32 + l31;
        int byte = d * 128 + s * 32 + hh * 16;
        byte ^= (((d & 7) ^ ((d >> 3) & 7)) << 4);
        short8 vf = *(const short8*)((const char*)Vt + byte);
        Oc[dt] = MFMA32(vf, pb, Oc[dt]);
      }
    }
    __builtin_amdgcn_s_setprio(0);

    __syncthreads();             // done with Vt & Kl[cur]; drains prefetch gl16
    if (pf) writeV(tid, vp, Vt);
    __syncthreads();
  }

  // --- epilogue: O^T regs -> ob[q][d], b64 stores (4 consecutive d per group) ---
  const int qg = q0 + wave * 32 + l31;
  if (qg < chunk_end) {
    const float inv = 1.f / l_run;
    unsigned short* op = ob + (long)qg * 1536 + h * 128;
#pragma unroll
    for (int dt = 0; dt < 4; ++dt) {
#pragma unroll
      for (int gblk = 0; gblk < 4; ++gblk) {
        int d = dt * 32 + gblk * 8 + hh * 4;
        unsigned int u0 = (unsigned int)f2bf(Oc[dt][4 * gblk]     * inv) |
                          ((unsigned int)f2bf(Oc[dt][4 * gblk + 1] * inv) << 16);
        unsigned int u1 = (unsigned int)f2bf(Oc[dt][4 * gblk + 2] * inv) |
                          ((unsigned int)f2bf(Oc[dt][4 * gblk + 3] * inv) << 16);
        u32x2 uu; uu[0] = u0; uu[1] = u1;
        *(u32x2*)(op + d) = uu;
      }
    }
  }
}

// ---------------- launch ----------------
extern "C" void kernel_launch(void* const* d_in, const int* in_sizes, int n_in,
                              void* d_out, int out_size, void* d_ws, size_t ws_size,
                              hipStream_t stream)
{
  const float* x  = (const float*)d_in[0];
  const float* Wq = (const float*)d_in[1];
  const float* bq = (const float*)d_in[2];
  const float* Wk = (const float*)d_in[3];
  const float* bk = (const float*)d_in[4];
  const float* Wv = (const float*)d_in[5];
  const float* bv = (const float*)d_in[6];
  const float* Wo = (const float*)d_in[7];
  const float* bo = (const float*)d_in[8];
  const float* gq = (const float*)d_in[9];
  const float* gk = (const float*)d_in[10];
  const float* fc = (const float*)d_in[11];
  const float* fs = (const float*)d_in[12];

  char* ws = (char*)d_ws;
  unsigned short* xb   = (unsigned short*)(ws);
  unsigned short* wcat = (unsigned short*)(ws + 21626880);
  unsigned short* wob  = (unsigned short*)(ws + 35782656);
  float*          bcat = (float*)(ws + 40501248);
  unsigned short* qkv  = (unsigned short*)(ws + 40519680);
  unsigned short* obuf = (unsigned short*)(ws + 105400320);

  cvt_f32_bf16<<<2048, 256, 0, stream>>>(x,  xb,   10813440 / 4);
  cvt_f32_bf16<<<1024, 256, 0, stream>>>(Wq, wcat,            2359296 / 4);
  cvt_f32_bf16<<<1024, 256, 0, stream>>>(Wk, wcat + 2359296,  2359296 / 4);
  cvt_f32_bf16<<<1024, 256, 0, stream>>>(Wv, wcat + 4718592,  2359296 / 4);
  cvt_f32_bf16<<<1024, 256, 0, stream>>>(Wo, wob,             2359296 / 4);
  hipMemcpyAsync(bcat,        bq, 1536 * 4, hipMemcpyDeviceToDevice, stream);
  hipMemcpyAsync(bcat + 1536, bk, 1536 * 4, hipMemcpyDeviceToDevice, stream);
  hipMemcpyAsync(bcat + 3072, bv, 1536 * 4, hipMemcpyDeviceToDevice, stream);

  gemm_bt<0><<<dim3(36, 55), 256, 0, stream>>>(xb, wcat, bcat, qkv, nullptr, 1536, 4608);

  const float qsc = (float)(1.4426950408889634 / sqrt(128.0));
  normrope<<<7040, 256, 0, stream>>>(qkv, gq, fc, fs, 0,    qsc);
  normrope<<<7040, 256, 0, stream>>>(qkv, gk, fc, fs, 1536, 1.0f);

  attn_kern<<<dim3(14, 4, 12), 256, 0, stream>>>(qkv, obuf);

  gemm_bt<1><<<dim3(12, 55), 256, 0, stream>>>(obuf, wob, bo, nullptr, (float*)d_out, 1536, 1536);
}

// Round 4
// 449.245 us; speedup vs baseline: 1.3353x; 1.0598x over previous
//
#include <hip/hip_runtime.h>
#include <math.h>

typedef __attribute__((ext_vector_type(8))) short short8;
typedef __attribute__((ext_vector_type(4))) float f32x4;
typedef __attribute__((ext_vector_type(16))) float f32x16;
typedef __attribute__((ext_vector_type(4))) float f4;
typedef __attribute__((ext_vector_type(4))) unsigned short us4;
typedef __attribute__((ext_vector_type(2))) unsigned int u32x2;

#define MFMA16(a,b,c) __builtin_amdgcn_mfma_f32_16x16x32_bf16(a,b,c,0,0,0)
#define MFMA32(a,b,c) __builtin_amdgcn_mfma_f32_32x32x16_bf16(a,b,c,0,0,0)

__device__ __forceinline__ unsigned short f2bf(float f) {
  unsigned int u = __float_as_uint(f);
  u = (u + 0x7FFFu + ((u >> 16) & 1u)) >> 16;   // RNE
  return (unsigned short)u;
}
__device__ __forceinline__ float bf2f(unsigned short b) {
  return __uint_as_float(((unsigned int)b) << 16);
}
// pack two f32 -> two bf16 in one u32 (round-half-up + v_perm byte select)
__device__ __forceinline__ unsigned int pk2(float a, float b) {
  unsigned int au = __float_as_uint(a) + 0x8000u;
  unsigned int bu = __float_as_uint(b) + 0x8000u;
  return __builtin_amdgcn_perm(bu, au, 0x07060302u);  // {b.hi16, a.hi16}
}

typedef const __attribute__((address_space(1))) unsigned int* gas_t;
typedef __attribute__((address_space(3))) unsigned int* las_t;
__device__ __forceinline__ void gl16(const void* g, void* l) {
  __builtin_amdgcn_global_load_lds((gas_t)g, (las_t)l, 16, 0, 0);
}

// ---------------- f32 -> bf16 convert ----------------
__global__ void cvt_f32_bf16(const float* __restrict__ in,
                             unsigned short* __restrict__ out, int n4) {
  int i = blockIdx.x * blockDim.x + threadIdx.x;
  const int stride = gridDim.x * blockDim.x;
  for (; i < n4; i += stride) {
    f4 v = ((const f4*)in)[i];
    us4 o;
    o[0] = f2bf(v[0]); o[1] = f2bf(v[1]); o[2] = f2bf(v[2]); o[3] = f2bf(v[3]);
    ((us4*)out)[i] = o;
  }
}

// ---------------- NT GEMM: out[m][n] = sum_k A[m][k]*B[n][k] + bias[n] ----------------
template<int F32OUT>
__global__ __launch_bounds__(256)
void gemm_bt(const unsigned short* __restrict__ A,
             const unsigned short* __restrict__ B,
             const float* __restrict__ bias,
             unsigned short* __restrict__ obf,
             float* __restrict__ of32,
             int K, int ldo)
{
  const int tid = threadIdx.x;
  const int wave = tid >> 6, lane = tid & 63, lg = lane >> 4, lr = lane & 15;
  const int wr = wave >> 1, wc = wave & 1;
  const int m0 = blockIdx.y * 128, n0 = blockIdx.x * 128;

  __shared__ __align__(16) unsigned short Al[128 * 32];
  __shared__ __align__(16) unsigned short Bl[128 * 32];

  f32x4 acc[4][4];
#pragma unroll
  for (int m = 0; m < 4; ++m)
#pragma unroll
    for (int n = 0; n < 4; ++n) acc[m][n] = (f32x4){0.f, 0.f, 0.f, 0.f};

  const int r0 = tid >> 2, r1 = (tid + 256) >> 2;
  const int c0 = (tid & 3) * 8;
  const long arow0 = (long)(m0 + r0) * K, arow1 = (long)(m0 + r1) * K;
  const long brow0 = (long)(n0 + r0) * K, brow1 = (long)(n0 + r1) * K;

  for (int k0 = 0; k0 < K; k0 += 32) {
    gl16(A + arow0 + k0 + c0, (char*)Al + tid * 16);
    gl16(A + arow1 + k0 + c0, (char*)Al + (tid + 256) * 16);
    gl16(B + brow0 + k0 + c0, (char*)Bl + tid * 16);
    gl16(B + brow1 + k0 + c0, (char*)Bl + (tid + 256) * 16);
    __syncthreads();
    short8 af[4], bf[4];
#pragma unroll
    for (int m = 0; m < 4; ++m)
      af[m] = *(const short8*)(Al + (wr * 64 + m * 16 + lr) * 32 + lg * 8);
#pragma unroll
    for (int n = 0; n < 4; ++n)
      bf[n] = *(const short8*)(Bl + (wc * 64 + n * 16 + lr) * 32 + lg * 8);
#pragma unroll
    for (int m = 0; m < 4; ++m)
#pragma unroll
      for (int n = 0; n < 4; ++n)
        acc[m][n] = MFMA16(af[m], bf[n], acc[m][n]);
    __syncthreads();
  }

#pragma unroll
  for (int n = 0; n < 4; ++n) {
    const int col = n0 + wc * 64 + n * 16 + lr;
    const float bs = bias[col];
#pragma unroll
    for (int m = 0; m < 4; ++m) {
      const int row = m0 + wr * 64 + m * 16 + lg * 4;
#pragma unroll
      for (int r = 0; r < 4; ++r) {
        float v = acc[m][n][r] + bs;
        if (F32OUT) of32[(long)(row + r) * ldo + col] = v;
        else        obf[(long)(row + r) * ldo + col] = f2bf(v);
      }
    }
  }
}

// ---------------- fused RMSNorm + RoPE ----------------
__global__ __launch_bounds__(256)
void normrope(unsigned short* __restrict__ qkv, const float* __restrict__ g,
              const float* __restrict__ fc, const float* __restrict__ fs,
              int colOff, float oscale)
{
  const int l = blockIdx.x, tid = threadIdx.x;
  __shared__ float rowbuf[1536];
  __shared__ float sred[4];
  unsigned short* rp = qkv + (long)l * 4608 + colOff;

  float ss = 0.f;
  if (tid < 192) {
    short8 v = *(const short8*)(rp + tid * 8);
#pragma unroll
    for (int e = 0; e < 8; ++e) {
      float f = bf2f((unsigned short)v[e]);
      rowbuf[tid * 8 + e] = f;
      ss += f * f;
    }
  }
#pragma unroll
  for (int m = 32; m; m >>= 1) ss += __shfl_xor(ss, m, 64);
  if ((tid & 63) == 0) sred[tid >> 6] = ss;
  __syncthreads();
  const float rs = rsqrtf((sred[0] + sred[1] + sred[2] + sred[3]) * (1.f / 1536.f) + 1e-6f);

  const int f_ = l / 880, rem = l % 880, h_ = rem / 40, w_ = rem % 40;
#pragma unroll
  for (int j = 0; j < 3; ++j) {
    int p = tid + j * 256;
    int head = p >> 6, c = p & 63;
    int e = head * 128 + 2 * c;
    int tr = (c < 22) ? f_ : ((c < 43) ? h_ : w_);
    float co = fc[tr * 64 + c], si = fs[tr * 64 + c];
    float xr = rowbuf[e] * rs * g[e];
    float xi = rowbuf[e + 1] * rs * g[e + 1];
    float yr = (xr * co - xi * si) * oscale;
    float yi = (xr * si + xi * co) * oscale;
    unsigned int pk = (unsigned int)f2bf(yr) | ((unsigned int)f2bf(yi) << 16);
    *(unsigned int*)(rp + e) = pk;
  }
}

// ---------------- attention staging helpers (256 threads) ----------------
__device__ __forceinline__ void issueK(const unsigned short* __restrict__ qkv,
                                       int h, int t, int kvlen, int woff, int tid,
                                       unsigned short* Kbuf)
{
#pragma unroll
  for (int i = 0; i < 4; ++i) {
    int s = i * 256 + tid;
    int kvl = s >> 4;
    int dc = (s & 15) ^ (kvl & 7);
    int j = t * 64 + kvl; j = j < kvlen ? j : kvlen - 1;
    int gk = j + (j >= 880 ? woff : 0);
    gl16(qkv + (long)gk * 4608 + 1536 + h * 128 + dc * 8, (char*)Kbuf + s * 16);
  }
}

__device__ __forceinline__ void loadV(const unsigned short* __restrict__ qkv,
                                      int h, int t, int kvlen, int woff, int tid,
                                      short8 vp[2][2])
{
#pragma unroll
  for (int i = 0; i < 2; ++i) {
    int task = i * 256 + tid;
    int dc = task & 15, kp = task >> 4;
    int kvl = kp * 2;
    int j0 = t * 64 + kvl, j1 = j0 + 1;
    j0 = j0 < kvlen ? j0 : kvlen - 1;
    j1 = j1 < kvlen ? j1 : kvlen - 1;
    int g0 = j0 + (j0 >= 880 ? woff : 0);
    int g1 = j1 + (j1 >= 880 ? woff : 0);
    vp[i][0] = *(const short8*)(qkv + (long)g0 * 4608 + 3072 + h * 128 + dc * 8);
    vp[i][1] = *(const short8*)(qkv + (long)g1 * 4608 + 3072 + h * 128 + dc * 8);
  }
}

__device__ __forceinline__ void writeV(int tid, short8 vp[2][2], unsigned short* Vt)
{
#pragma unroll
  for (int i = 0; i < 2; ++i) {
    int task = i * 256 + tid;
    int dc = task & 15, kp = task >> 4;
    int kvl = kp * 2;
#pragma unroll
    for (int e = 0; e < 8; ++e) {
      int d = dc * 8 + e;
      int byte = d * 128 + kvl * 2;
      byte ^= (((d & 7) ^ ((d >> 3) & 7)) << 4);
      *(unsigned int*)((char*)Vt + byte) =
          (unsigned int)(unsigned short)vp[i][0][e] |
          ((unsigned int)(unsigned short)vp[i][1][e] << 16);
    }
  }
}

// ---------------- chunked sink+window attention, 32x32 swapped-operand ----------------
// grid (14 qtiles, 4 chunks, 12 heads); 4 waves x 32 q-rows; KV tile 64.
// K and V both double-buffered -> ONE barrier per tile. Defer-max rescale (T13).
__global__ __launch_bounds__(256, 2)
void attn_kern(const unsigned short* __restrict__ qkv,
               unsigned short* __restrict__ ob)
{
  const int qt = blockIdx.x, ci = blockIdx.y, h = blockIdx.z;
  const int tid = threadIdx.x, wave = tid >> 6, lane = tid & 63;
  const int l31 = lane & 31, hh = lane >> 5;
  const int chunk_start = ci * 1760, chunk_end = chunk_start + 1760;
  const int wstart = (ci == 0) ? 880 : ci * 1760;
  const int woff = wstart - 880;
  const int kvlen = 880 + (chunk_end - wstart);     // 1760 or 2640
  const int q0 = chunk_start + qt * 128;

  __shared__ __align__(16) unsigned short Kl[2][64 * 128];
  __shared__ __align__(16) unsigned short Vt[2][128 * 64];

  int qr = q0 + wave * 32 + l31;
  if (qr >= chunk_end) qr = chunk_end - 1;
  const unsigned short* qp = qkv + (long)qr * 4608 + h * 128;
  short8 qf[8];
#pragma unroll
  for (int st = 0; st < 8; ++st) qf[st] = *(const short8*)(qp + st * 16 + hh * 8);

  f32x16 Oc[4];
#pragma unroll
  for (int i = 0; i < 4; ++i)
#pragma unroll
    for (int j = 0; j < 16; ++j) Oc[i][j] = 0.f;
  float m_run = -1e30f, l_run = 0.f;

  const int nt = (kvlen + 63) >> 6;
  short8 vp[2][2];
  issueK(qkv, h, 0, kvlen, woff, tid, &Kl[0][0]);
  loadV(qkv, h, 0, kvlen, woff, tid, vp);
  writeV(tid, vp, &Vt[0][0]);
  __syncthreads();

  for (int t = 0; t < nt; ++t) {
    const int cur = t & 1;
    const bool pf = (t + 1 < nt);
    if (pf) {
      issueK(qkv, h, t + 1, kvlen, woff, tid, &Kl[cur ^ 1][0]);
      loadV(qkv, h, t + 1, kvlen, woff, tid, vp);
    }

    // --- S^T = K . Q ---
    f32x16 s0, s1;
#pragma unroll
    for (int j = 0; j < 16; ++j) { s0[j] = 0.f; s1[j] = 0.f; }
    __builtin_amdgcn_s_setprio(1);
#pragma unroll
    for (int st = 0; st < 8; ++st) {
      int off = 32 * st + 16 * hh;
      int b0 = l31 * 256 + (off ^ ((l31 & 7) << 4));
      short8 k0 = *(const short8*)((const char*)&Kl[cur][0] + b0);
      s0 = MFMA32(k0, qf[st], s0);
      int b1 = (32 + l31) * 256 + (off ^ ((l31 & 7) << 4));
      short8 k1 = *(const short8*)((const char*)&Kl[cur][0] + b1);
      s1 = MFMA32(k1, qf[st], s1);
    }
    __builtin_amdgcn_s_setprio(0);

    // --- tail mask (uniform branch) ---
    if (t * 64 + 64 > kvlen) {
#pragma unroll
      for (int r = 0; r < 16; ++r) {
        int kv0 = t * 64 + (r & 3) + 8 * (r >> 2) + 4 * hh;
        if (kv0 >= kvlen)      s0[r] = -1e30f;
        if (kv0 + 32 >= kvlen) s1[r] = -1e30f;
      }
    }

    // --- tile max (tree) + cross-half exchange ---
    float mx[16];
#pragma unroll
    for (int r = 0; r < 16; ++r) mx[r] = fmaxf(s0[r], s1[r]);
#pragma unroll
    for (int w = 8; w; w >>= 1)
#pragma unroll
      for (int r = 0; r < w; ++r) mx[r] = fmaxf(mx[r], mx[r + w]);
    float pm = fmaxf(mx[0], __shfl_xor(mx[0], 32, 64));

    // --- defer-max (T13): rescale only when max grew past threshold ---
    const bool defer = __all(pm <= m_run + 8.f);
    const float mn = defer ? m_run : fmaxf(m_run, pm);

    // --- exp2 + sum (tree) ---
#pragma unroll
    for (int r = 0; r < 16; ++r) {
      s0[r] = __builtin_amdgcn_exp2f(s0[r] - mn);
      s1[r] = __builtin_amdgcn_exp2f(s1[r] - mn);
    }
    float sm[16];
#pragma unroll
    for (int r = 0; r < 16; ++r) sm[r] = s0[r] + s1[r];
#pragma unroll
    for (int w = 8; w; w >>= 1)
#pragma unroll
      for (int r = 0; r < w; ++r) sm[r] += sm[r + w];
    float sum = sm[0] + __shfl_xor(sm[0], 32, 64);

    if (defer) {
      l_run += sum;
    } else {
      float al = __builtin_amdgcn_exp2f(m_run - mn);
      l_run = l_run * al + sum;
      m_run = mn;
#pragma unroll
      for (int i = 0; i < 4; ++i)
#pragma unroll
        for (int j = 0; j < 16; ++j) Oc[i][j] *= al;
    }

    // --- pack P to bf16 words (v_perm) ---
    unsigned int w0[8], w1[8];
#pragma unroll
    for (int m = 0; m < 8; ++m) {
      w0[m] = pk2(s0[2 * m], s0[2 * m + 1]);
      w1[m] = pk2(s1[2 * m], s1[2 * m + 1]);
    }

    // --- prefetch-write next V tile (no barrier needed: dbuf) ---
    if (pf) writeV(tid, vp, &Vt[cur ^ 1][0]);

    // --- O^T += V^T . P^T ---
    __builtin_amdgcn_s_setprio(1);
#pragma unroll
    for (int s = 0; s < 4; ++s) {
      const unsigned int* w = (s < 2) ? w0 : w1;
      const int lo4 = (s & 1) * 4;
      unsigned int x0 = __shfl_xor(w[lo4 + 2], 32, 64);
      unsigned int x1 = __shfl_xor(w[lo4 + 3], 32, 64);
      unsigned int y0 = __shfl_xor(w[lo4],     32, 64);
      unsigned int y1 = __shfl_xor(w[lo4 + 1], 32, 64);
      unsigned int fw[4];
      fw[0] = hh ? x0 : w[lo4];
      fw[1] = hh ? x1 : w[lo4 + 1];
      fw[2] = hh ? w[lo4 + 2] : y0;
      fw[3] = hh ? w[lo4 + 3] : y1;
      short8 pb = *(const short8*)fw;
#pragma unroll
      for (int dt = 0; dt < 4; ++dt) {
        int d = dt * 32 + l31;
        int byte = d * 128 + s * 32 + hh * 16;
        byte ^= (((d & 7) ^ ((d >> 3) & 7)) << 4);
        short8 vf = *(const short8*)((const char*)&Vt[cur][0] + byte);
        Oc[dt] = MFMA32(vf, pb, Oc[dt]);
      }
    }
    __builtin_amdgcn_s_setprio(0);

    __syncthreads();   // drains gl16 prefetch (vmcnt0) + V lds writes; flips buffers
  }

  // --- epilogue ---
  const int qg = q0 + wave * 32 + l31;
  if (qg < chunk_end) {
    const float inv = 1.f / l_run;
    unsigned short* op = ob + (long)qg * 1536 + h * 128;
#pragma unroll
    for (int dt = 0; dt < 4; ++dt) {
#pragma unroll
      for (int gblk = 0; gblk < 4; ++gblk) {
        int d = dt * 32 + gblk * 8 + hh * 4;
        unsigned int u0 = pk2(Oc[dt][4 * gblk]     * inv, Oc[dt][4 * gblk + 1] * inv);
        unsigned int u1 = pk2(Oc[dt][4 * gblk + 2] * inv, Oc[dt][4 * gblk + 3] * inv);
        u32x2 uu; uu[0] = u0; uu[1] = u1;
        *(u32x2*)(op + d) = uu;
      }
    }
  }
}

// ---------------- launch ----------------
extern "C" void kernel_launch(void* const* d_in, const int* in_sizes, int n_in,
                              void* d_out, int out_size, void* d_ws, size_t ws_size,
                              hipStream_t stream)
{
  const float* x  = (const float*)d_in[0];
  const float* Wq = (const float*)d_in[1];
  const float* bq = (const float*)d_in[2];
  const float* Wk = (const float*)d_in[3];
  const float* bk = (const float*)d_in[4];
  const float* Wv = (const float*)d_in[5];
  const float* bv = (const float*)d_in[6];
  const float* Wo = (const float*)d_in[7];
  const float* bo = (const float*)d_in[8];
  const float* gq = (const float*)d_in[9];
  const float* gk = (const float*)d_in[10];
  const float* fc = (const float*)d_in[11];
  const float* fs = (const float*)d_in[12];

  char* ws = (char*)d_ws;
  unsigned short* xb   = (unsigned short*)(ws);
  unsigned short* wcat = (unsigned short*)(ws + 21626880);
  unsigned short* wob  = (unsigned short*)(ws + 35782656);
  float*          bcat = (float*)(ws + 40501248);
  unsigned short* qkv  = (unsigned short*)(ws + 40519680);
  unsigned short* obuf = (unsigned short*)(ws + 105400320);

  cvt_f32_bf16<<<2048, 256, 0, stream>>>(x,  xb,   10813440 / 4);
  cvt_f32_bf16<<<1024, 256, 0, stream>>>(Wq, wcat,            2359296 / 4);
  cvt_f32_bf16<<<1024, 256, 0, stream>>>(Wk, wcat + 2359296,  2359296 / 4);
  cvt_f32_bf16<<<1024, 256, 0, stream>>>(Wv, wcat + 4718592,  2359296 / 4);
  cvt_f32_bf16<<<1024, 256, 0, stream>>>(Wo, wob,             2359296 / 4);
  hipMemcpyAsync(bcat,        bq, 1536 * 4, hipMemcpyDeviceToDevice, stream);
  hipMemcpyAsync(bcat + 1536, bk, 1536 * 4, hipMemcpyDeviceToDevice, stream);
  hipMemcpyAsync(bcat + 3072, bv, 1536 * 4, hipMemcpyDeviceToDevice, stream);

  gemm_bt<0><<<dim3(36, 55), 256, 0, stream>>>(xb, wcat, bcat, qkv, nullptr, 1536, 4608);

  const float qsc = (float)(1.4426950408889634 / sqrt(128.0));
  normrope<<<7040, 256, 0, stream>>>(qkv, gq, fc, fs, 0,    qsc);
  normrope<<<7040, 256, 0, stream>>>(qkv, gk, fc, fs, 1536, 1.0f);

  attn_kern<<<dim3(14, 4, 12), 256, 0, stream>>>(qkv, obuf);

  gemm_bt<1><<<dim3(12, 55), 256, 0, stream>>>(obuf, wob, bo, nullptr, (float*)d_out, 1536, 1536);
}

// Round 5
// 442.547 us; speedup vs baseline: 1.3555x; 1.0151x over previous
//
#include <hip/hip_runtime.h>
#include <math.h>

typedef __attribute__((ext_vector_type(8))) short short8;
typedef __attribute__((ext_vector_type(4))) float f32x4;
typedef __attribute__((ext_vector_type(16))) float f32x16;
typedef __attribute__((ext_vector_type(4))) float f4;
typedef __attribute__((ext_vector_type(4))) unsigned short us4;
typedef __attribute__((ext_vector_type(2))) unsigned int u32x2;

#define MFMA16(a,b,c) __builtin_amdgcn_mfma_f32_16x16x32_bf16(a,b,c,0,0,0)
#define MFMA32(a,b,c) __builtin_amdgcn_mfma_f32_32x32x16_bf16(a,b,c,0,0,0)

__device__ __forceinline__ unsigned short f2bf(float f) {
  unsigned int u = __float_as_uint(f);
  u = (u + 0x7FFFu + ((u >> 16) & 1u)) >> 16;   // RNE
  return (unsigned short)u;
}
__device__ __forceinline__ float bf2f(unsigned short b) {
  return __uint_as_float(((unsigned int)b) << 16);
}
// pack two f32 -> two bf16 in one u32 (round-half-up + v_perm byte select)
__device__ __forceinline__ unsigned int pk2(float a, float b) {
  unsigned int au = __float_as_uint(a) + 0x8000u;
  unsigned int bu = __float_as_uint(b) + 0x8000u;
  return __builtin_amdgcn_perm(bu, au, 0x07060302u);  // {b.hi16, a.hi16}
}

typedef const __attribute__((address_space(1))) unsigned int* gas_t;
typedef __attribute__((address_space(3))) unsigned int* las_t;
__device__ __forceinline__ void gl16(const void* g, void* l) {
  __builtin_amdgcn_global_load_lds((gas_t)g, (las_t)l, 16, 0, 0);
}

// ---------------- f32 -> bf16 convert ----------------
__global__ void cvt_f32_bf16(const float* __restrict__ in,
                             unsigned short* __restrict__ out, int n4) {
  int i = blockIdx.x * blockDim.x + threadIdx.x;
  const int stride = gridDim.x * blockDim.x;
  for (; i < n4; i += stride) {
    f4 v = ((const f4*)in)[i];
    us4 o;
    o[0] = f2bf(v[0]); o[1] = f2bf(v[1]); o[2] = f2bf(v[2]); o[3] = f2bf(v[3]);
    ((us4*)out)[i] = o;
  }
}

// ---------------- NT GEMM: out[m][n] = sum_k A[m][k]*B[n][k] + bias[n] ----------------
template<int F32OUT>
__global__ __launch_bounds__(256)
void gemm_bt(const unsigned short* __restrict__ A,
             const unsigned short* __restrict__ B,
             const float* __restrict__ bias,
             unsigned short* __restrict__ obf,
             float* __restrict__ of32,
             int K, int ldo)
{
  const int tid = threadIdx.x;
  const int wave = tid >> 6, lane = tid & 63, lg = lane >> 4, lr = lane & 15;
  const int wr = wave >> 1, wc = wave & 1;
  const int m0 = blockIdx.y * 128, n0 = blockIdx.x * 128;

  __shared__ __align__(16) unsigned short Al[128 * 32];
  __shared__ __align__(16) unsigned short Bl[128 * 32];

  f32x4 acc[4][4];
#pragma unroll
  for (int m = 0; m < 4; ++m)
#pragma unroll
    for (int n = 0; n < 4; ++n) acc[m][n] = (f32x4){0.f, 0.f, 0.f, 0.f};

  const int r0 = tid >> 2, r1 = (tid + 256) >> 2;
  const int c0 = (tid & 3) * 8;
  const long arow0 = (long)(m0 + r0) * K, arow1 = (long)(m0 + r1) * K;
  const long brow0 = (long)(n0 + r0) * K, brow1 = (long)(n0 + r1) * K;

  for (int k0 = 0; k0 < K; k0 += 32) {
    gl16(A + arow0 + k0 + c0, (char*)Al + tid * 16);
    gl16(A + arow1 + k0 + c0, (char*)Al + (tid + 256) * 16);
    gl16(B + brow0 + k0 + c0, (char*)Bl + tid * 16);
    gl16(B + brow1 + k0 + c0, (char*)Bl + (tid + 256) * 16);
    __syncthreads();
    short8 af[4], bf[4];
#pragma unroll
    for (int m = 0; m < 4; ++m)
      af[m] = *(const short8*)(Al + (wr * 64 + m * 16 + lr) * 32 + lg * 8);
#pragma unroll
    for (int n = 0; n < 4; ++n)
      bf[n] = *(const short8*)(Bl + (wc * 64 + n * 16 + lr) * 32 + lg * 8);
#pragma unroll
    for (int m = 0; m < 4; ++m)
#pragma unroll
      for (int n = 0; n < 4; ++n)
        acc[m][n] = MFMA16(af[m], bf[n], acc[m][n]);
    __syncthreads();
  }

#pragma unroll
  for (int n = 0; n < 4; ++n) {
    const int col = n0 + wc * 64 + n * 16 + lr;
    const float bs = bias[col];
#pragma unroll
    for (int m = 0; m < 4; ++m) {
      const int row = m0 + wr * 64 + m * 16 + lg * 4;
#pragma unroll
      for (int r = 0; r < 4; ++r) {
        float v = acc[m][n][r] + bs;
        if (F32OUT) of32[(long)(row + r) * ldo + col] = v;
        else        obf[(long)(row + r) * ldo + col] = f2bf(v);
      }
    }
  }
}

// ---------------- fused RMSNorm + RoPE ----------------
__global__ __launch_bounds__(256)
void normrope(unsigned short* __restrict__ qkv, const float* __restrict__ g,
              const float* __restrict__ fc, const float* __restrict__ fs,
              int colOff, float oscale)
{
  const int l = blockIdx.x, tid = threadIdx.x;
  __shared__ float rowbuf[1536];
  __shared__ float sred[4];
  unsigned short* rp = qkv + (long)l * 4608 + colOff;

  float ss = 0.f;
  if (tid < 192) {
    short8 v = *(const short8*)(rp + tid * 8);
#pragma unroll
    for (int e = 0; e < 8; ++e) {
      float f = bf2f((unsigned short)v[e]);
      rowbuf[tid * 8 + e] = f;
      ss += f * f;
    }
  }
#pragma unroll
  for (int m = 32; m; m >>= 1) ss += __shfl_xor(ss, m, 64);
  if ((tid & 63) == 0) sred[tid >> 6] = ss;
  __syncthreads();
  const float rs = rsqrtf((sred[0] + sred[1] + sred[2] + sred[3]) * (1.f / 1536.f) + 1e-6f);

  const int f_ = l / 880, rem = l % 880, h_ = rem / 40, w_ = rem % 40;
#pragma unroll
  for (int j = 0; j < 3; ++j) {
    int p = tid + j * 256;
    int head = p >> 6, c = p & 63;
    int e = head * 128 + 2 * c;
    int tr = (c < 22) ? f_ : ((c < 43) ? h_ : w_);
    float co = fc[tr * 64 + c], si = fs[tr * 64 + c];
    float xr = rowbuf[e] * rs * g[e];
    float xi = rowbuf[e + 1] * rs * g[e + 1];
    float yr = (xr * co - xi * si) * oscale;
    float yi = (xr * si + xi * co) * oscale;
    unsigned int pk = (unsigned int)f2bf(yr) | ((unsigned int)f2bf(yi) << 16);
    *(unsigned int*)(rp + e) = pk;
  }
}

// ---------------- attention staging helpers (256 threads) ----------------
__device__ __forceinline__ void issueK(const unsigned short* __restrict__ qkv,
                                       int h, int t, int kvlen, int woff, int tid,
                                       unsigned short* Kbuf)
{
#pragma unroll
  for (int i = 0; i < 4; ++i) {
    int s = i * 256 + tid;
    int kvl = s >> 4;
    int dc = (s & 15) ^ (kvl & 7);
    int j = t * 64 + kvl; j = j < kvlen ? j : kvlen - 1;
    int gk = j + (j >= 880 ? woff : 0);
    gl16(qkv + (long)gk * 4608 + 1536 + h * 128 + dc * 8, (char*)Kbuf + s * 16);
  }
}

__device__ __forceinline__ void loadV(const unsigned short* __restrict__ qkv,
                                      int h, int t, int kvlen, int woff, int tid,
                                      short8 vp[2][2])
{
#pragma unroll
  for (int i = 0; i < 2; ++i) {
    int task = i * 256 + tid;
    int dc = task & 15, kp = task >> 4;
    int kvl = kp * 2;
    int j0 = t * 64 + kvl, j1 = j0 + 1;
    j0 = j0 < kvlen ? j0 : kvlen - 1;
    j1 = j1 < kvlen ? j1 : kvlen - 1;
    int g0 = j0 + (j0 >= 880 ? woff : 0);
    int g1 = j1 + (j1 >= 880 ? woff : 0);
    vp[i][0] = *(const short8*)(qkv + (long)g0 * 4608 + 3072 + h * 128 + dc * 8);
    vp[i][1] = *(const short8*)(qkv + (long)g1 * 4608 + 3072 + h * 128 + dc * 8);
  }
}

__device__ __forceinline__ void writeV(int tid, short8 vp[2][2], unsigned short* Vt)
{
#pragma unroll
  for (int i = 0; i < 2; ++i) {
    int task = i * 256 + tid;
    int dc = task & 15, kp = task >> 4;
    int kvl = kp * 2;
#pragma unroll
    for (int e = 0; e < 8; ++e) {
      int d = dc * 8 + e;
      int byte = d * 128 + kvl * 2;
      byte ^= (((d & 7) ^ ((d >> 3) & 7)) << 4);
      *(unsigned int*)((char*)Vt + byte) =
          (unsigned int)(unsigned short)vp[i][0][e] |
          ((unsigned int)(unsigned short)vp[i][1][e] << 16);
    }
  }
}

// ---------------- chunked sink+window attention, 32x32 swapped-operand ----------------
// grid (14 qtiles, 4 chunks, 12 heads); 4 waves x 32 q-rows; KV tile 64.
// Cross-tile S-pipeline (T15): iter t = QK(t+1) || softmax(t) || PV(t).
__global__ __launch_bounds__(256, 2)
void attn_kern(const unsigned short* __restrict__ qkv,
               unsigned short* __restrict__ ob)
{
  const int qt = blockIdx.x, ci = blockIdx.y, h = blockIdx.z;
  const int tid = threadIdx.x, wave = tid >> 6, lane = tid & 63;
  const int l31 = lane & 31, hh = lane >> 5;
  const int chunk_start = ci * 1760, chunk_end = chunk_start + 1760;
  const int wstart = (ci == 0) ? 880 : ci * 1760;
  const int woff = wstart - 880;
  const int kvlen = 880 + (chunk_end - wstart);     // 1760 or 2640
  const int q0 = chunk_start + qt * 128;

  __shared__ __align__(16) unsigned short Kl[2][64 * 128];
  __shared__ __align__(16) unsigned short Vt[2][128 * 64];

  int qr = q0 + wave * 32 + l31;
  if (qr >= chunk_end) qr = chunk_end - 1;
  const unsigned short* qp = qkv + (long)qr * 4608 + h * 128;
  short8 qf[8];
#pragma unroll
  for (int st = 0; st < 8; ++st) qf[st] = *(const short8*)(qp + st * 16 + hh * 8);

  f32x16 Oc[4];
#pragma unroll
  for (int i = 0; i < 4; ++i)
#pragma unroll
    for (int j = 0; j < 16; ++j) Oc[i][j] = 0.f;
  float m_run = -1e30f, l_run = 0.f;
  unsigned int w0[8], w1[8];

  // --- S^T = K . Q for tile t from Kl[cur]; tail-masked ---
  auto computeQK = [&](int t, int cur, f32x16* S0, f32x16* S1) {
    f32x16 a0, a1;
#pragma unroll
    for (int j = 0; j < 16; ++j) { a0[j] = 0.f; a1[j] = 0.f; }
    __builtin_amdgcn_s_setprio(1);
#pragma unroll
    for (int st = 0; st < 8; ++st) {
      int off = 32 * st + 16 * hh;
      int b0 = l31 * 256 + (off ^ ((l31 & 7) << 4));
      short8 k0 = *(const short8*)((const char*)&Kl[cur][0] + b0);
      a0 = MFMA32(k0, qf[st], a0);
      int b1 = (32 + l31) * 256 + (off ^ ((l31 & 7) << 4));
      short8 k1 = *(const short8*)((const char*)&Kl[cur][0] + b1);
      a1 = MFMA32(k1, qf[st], a1);
    }
    __builtin_amdgcn_s_setprio(0);
    if (t * 64 + 64 > kvlen) {       // uniform: tail tile only
#pragma unroll
      for (int r = 0; r < 16; ++r) {
        int kv0 = t * 64 + (r & 3) + 8 * (r >> 2) + 4 * hh;
        if (kv0 >= kvlen)      a0[r] = -1e30f;
        if (kv0 + 32 >= kvlen) a1[r] = -1e30f;
      }
    }
    *S0 = a0; *S1 = a1;
  };

  // --- online softmax on a finished S tile; packs P into w0/w1; rescales Oc ---
  auto finishTile = [&](f32x16& s0f, f32x16& s1f) {
    float mx[16];
#pragma unroll
    for (int r = 0; r < 16; ++r) mx[r] = fmaxf(s0f[r], s1f[r]);
#pragma unroll
    for (int w = 8; w; w >>= 1)
#pragma unroll
      for (int r = 0; r < w; ++r) mx[r] = fmaxf(mx[r], mx[r + w]);
    float pm = fmaxf(mx[0], __shfl_xor(mx[0], 32, 64));
    const bool defer = __all(pm <= m_run + 8.f);   // T13 (log2 domain)
    const float mn = defer ? m_run : fmaxf(m_run, pm);
#pragma unroll
    for (int r = 0; r < 16; ++r) {
      s0f[r] = __builtin_amdgcn_exp2f(s0f[r] - mn);
      s1f[r] = __builtin_amdgcn_exp2f(s1f[r] - mn);
    }
    float sm[16];
#pragma unroll
    for (int r = 0; r < 16; ++r) sm[r] = s0f[r] + s1f[r];
#pragma unroll
    for (int w = 8; w; w >>= 1)
#pragma unroll
      for (int r = 0; r < w; ++r) sm[r] += sm[r + w];
    float sum = sm[0] + __shfl_xor(sm[0], 32, 64);
    if (defer) {
      l_run += sum;
    } else {
      float al = __builtin_amdgcn_exp2f(m_run - mn);
      l_run = l_run * al + sum;
      m_run = mn;
#pragma unroll
      for (int i = 0; i < 4; ++i)
#pragma unroll
        for (int j = 0; j < 16; ++j) Oc[i][j] *= al;
    }
#pragma unroll
    for (int m = 0; m < 8; ++m) {
      w0[m] = pk2(s0f[2 * m], s0f[2 * m + 1]);
      w1[m] = pk2(s1f[2 * m], s1f[2 * m + 1]);
    }
  };

  // --- O^T += V^T . P^T from Vt[cur] using w0/w1 ---
  auto doPV = [&](int cur) {
    __builtin_amdgcn_s_setprio(1);
#pragma unroll
    for (int s = 0; s < 4; ++s) {
      const unsigned int* w = (s < 2) ? w0 : w1;
      const int lo4 = (s & 1) * 4;
      unsigned int x0 = __shfl_xor(w[lo4 + 2], 32, 64);
      unsigned int x1 = __shfl_xor(w[lo4 + 3], 32, 64);
      unsigned int y0 = __shfl_xor(w[lo4],     32, 64);
      unsigned int y1 = __shfl_xor(w[lo4 + 1], 32, 64);
      unsigned int fw[4];
      fw[0] = hh ? x0 : w[lo4];
      fw[1] = hh ? x1 : w[lo4 + 1];
      fw[2] = hh ? w[lo4 + 2] : y0;
      fw[3] = hh ? w[lo4 + 3] : y1;
      short8 pb = *(const short8*)fw;
#pragma unroll
      for (int dt = 0; dt < 4; ++dt) {
        int d = dt * 32 + l31;
        int byte = d * 128 + s * 32 + hh * 16;
        byte ^= (((d & 7) ^ ((d >> 3) & 7)) << 4);
        short8 vf = *(const short8*)((const char*)&Vt[cur][0] + byte);
        Oc[dt] = MFMA32(vf, pb, Oc[dt]);
      }
    }
    __builtin_amdgcn_s_setprio(0);
  };

  const int nt = (kvlen + 63) >> 6;
  short8 vp[2][2];

  // prologue: stage K0,K1,V0; compute QK(0)
  issueK(qkv, h, 0, kvlen, woff, tid, &Kl[0][0]);
  if (nt > 1) issueK(qkv, h, 1, kvlen, woff, tid, &Kl[1][0]);
  loadV(qkv, h, 0, kvlen, woff, tid, vp);
  writeV(tid, vp, &Vt[0][0]);
  __syncthreads();

  f32x16 sp0, sp1;
  computeQK(0, 0, &sp0, &sp1);
  __syncthreads();    // all waves done reading Kl[0] before iter-0 prefetch overwrites it

  for (int t = 0; t < nt - 1; ++t) {
    const int cur = t & 1;
    if (t + 2 < nt) issueK(qkv, h, t + 2, kvlen, woff, tid, &Kl[cur][0]);
    loadV(qkv, h, t + 1, kvlen, woff, tid, vp);

    f32x16 sc0, sc1;
    computeQK(t + 1, cur ^ 1, &sc0, &sc1);   // MFMA pipe busy...
    finishTile(sp0, sp1);                    // ...while VALU runs softmax(t)
    writeV(tid, vp, &Vt[cur ^ 1][0]);
    doPV(cur);                               // PV(t)
    __syncthreads();                         // drains gl16 + V writes; flips buffers
    sp0 = sc0; sp1 = sc1;
  }
  finishTile(sp0, sp1);
  doPV((nt - 1) & 1);

  // --- epilogue ---
  const int qg = q0 + wave * 32 + l31;
  if (qg < chunk_end) {
    const float inv = 1.f / l_run;
    unsigned short* op = ob + (long)qg * 1536 + h * 128;
#pragma unroll
    for (int dt = 0; dt < 4; ++dt) {
#pragma unroll
      for (int gblk = 0; gblk < 4; ++gblk) {
        int d = dt * 32 + gblk * 8 + hh * 4;
        unsigned int u0 = pk2(Oc[dt][4 * gblk]     * inv, Oc[dt][4 * gblk + 1] * inv);
        unsigned int u1 = pk2(Oc[dt][4 * gblk + 2] * inv, Oc[dt][4 * gblk + 3] * inv);
        u32x2 uu; uu[0] = u0; uu[1] = u1;
        *(u32x2*)(op + d) = uu;
      }
    }
  }
}

// ---------------- launch ----------------
extern "C" void kernel_launch(void* const* d_in, const int* in_sizes, int n_in,
                              void* d_out, int out_size, void* d_ws, size_t ws_size,
                              hipStream_t stream)
{
  const float* x  = (const float*)d_in[0];
  const float* Wq = (const float*)d_in[1];
  const float* bq = (const float*)d_in[2];
  const float* Wk = (const float*)d_in[3];
  const float* bk = (const float*)d_in[4];
  const float* Wv = (const float*)d_in[5];
  const float* bv = (const float*)d_in[6];
  const float* Wo = (const float*)d_in[7];
  const float* bo = (const float*)d_in[8];
  const float* gq = (const float*)d_in[9];
  const float* gk = (const float*)d_in[10];
  const float* fc = (const float*)d_in[11];
  const float* fs = (const float*)d_in[12];

  char* ws = (char*)d_ws;
  unsigned short* xb   = (unsigned short*)(ws);
  unsigned short* wcat = (unsigned short*)(ws + 21626880);
  unsigned short* wob  = (unsigned short*)(ws + 35782656);
  float*          bcat = (float*)(ws + 40501248);
  unsigned short* qkv  = (unsigned short*)(ws + 40519680);
  unsigned short* obuf = (unsigned short*)(ws + 105400320);

  cvt_f32_bf16<<<2048, 256, 0, stream>>>(x,  xb,   10813440 / 4);
  cvt_f32_bf16<<<1024, 256, 0, stream>>>(Wq, wcat,            2359296 / 4);
  cvt_f32_bf16<<<1024, 256, 0, stream>>>(Wk, wcat + 2359296,  2359296 / 4);
  cvt_f32_bf16<<<1024, 256, 0, stream>>>(Wv, wcat + 4718592,  2359296 / 4);
  cvt_f32_bf16<<<1024, 256, 0, stream>>>(Wo, wob,             2359296 / 4);
  hipMemcpyAsync(bcat,        bq, 1536 * 4, hipMemcpyDeviceToDevice, stream);
  hipMemcpyAsync(bcat + 1536, bk, 1536 * 4, hipMemcpyDeviceToDevice, stream);
  hipMemcpyAsync(bcat + 3072, bv, 1536 * 4, hipMemcpyDeviceToDevice, stream);

  gemm_bt<0><<<dim3(36, 55), 256, 0, stream>>>(xb, wcat, bcat, qkv, nullptr, 1536, 4608);

  const float qsc = (float)(1.4426950408889634 / sqrt(128.0));
  normrope<<<7040, 256, 0, stream>>>(qkv, gq, fc, fs, 0,    qsc);
  normrope<<<7040, 256, 0, stream>>>(qkv, gk, fc, fs, 1536, 1.0f);

  attn_kern<<<dim3(14, 4, 12), 256, 0, stream>>>(qkv, obuf);

  gemm_bt<1><<<dim3(12, 55), 256, 0, stream>>>(obuf, wob, bo, nullptr, (float*)d_out, 1536, 1536);
}